// Round 3
// baseline (103.434 us; speedup 1.0000x reference)
//
#include <hip/hip_runtime.h>

#define T_STEPS 1024
#define B_ELEMS 32768
#define K_SPLIT 4                 // time chunks (redundant warm-up compute)
#define NS (T_STEPS / K_SPLIT)    // 256 stored steps per chunk
#define STEP 0.5f

typedef float f32x4 __attribute__((ext_vector_type(4)));

__global__ __launch_bounds__(256) void seir_euler_kernel(
    const float* __restrict__ initial,   // (4, B)
    const float* __restrict__ beta,
    const float* __restrict__ gamma,
    const float* __restrict__ sigma,
    f32x4* __restrict__ out,             // (T*B) rows of 4 floats
    int B)
{
    const int b = blockIdx.x * 64 + threadIdx.x;   // lane-contiguous batch idx
    const int c = threadIdx.y;                     // time chunk 0..3

    const float bb = beta[0];
    const float gg = gamma[0];
    const float ss = sigma[0];

    float S = initial[0 * B + b];
    float E = initial[1 * B + b];
    float I = initial[2 * B + b];
    float R = initial[3 * B + b];

    // Warm-up: advance serially (bit-exact, same op order) to this chunk's start.
    const int start = c * NS;
    for (int n = 0; n < start; ++n) {
        float bSI = bb * S * I;
        float sE  = ss * E;
        float gI  = gg * I;
        float Sn = S - bSI * STEP;
        float En = E + (bSI - sE) * STEP;
        float In = I + (sE - gI) * STEP;
        float Rn = R + gI * STEP;
        S = Sn; E = En; I = In; R = Rn;
    }

    // Stored phase: row n = state after n steps; store, then advance.
    size_t idx = (size_t)start * B + b;
#pragma unroll 2
    for (int n = 0; n < NS; ++n, idx += B) {
        f32x4 v = {S, E, I, R};
        __builtin_nontemporal_store(v, &out[idx]);
        float bSI = bb * S * I;
        float sE  = ss * E;
        float gI  = gg * I;
        float Sn = S - bSI * STEP;
        float En = E + (bSI - sE) * STEP;
        float In = I + (sE - gI) * STEP;
        float Rn = R + gI * STEP;
        S = Sn; E = En; I = In; R = Rn;
    }
}

extern "C" void kernel_launch(void* const* d_in, const int* in_sizes, int n_in,
                              void* d_out, int out_size, void* d_ws, size_t ws_size,
                              hipStream_t stream)
{
    const float* initial = (const float*)d_in[0];
    const float* beta    = (const float*)d_in[1];
    const float* gamma   = (const float*)d_in[2];
    const float* sigma   = (const float*)d_in[3];
    f32x4* out = (f32x4*)d_out;

    const int B = B_ELEMS;
    dim3 block(64, K_SPLIT);            // 4 waves/block: same b-range, 4 time chunks
    dim3 grid(B / 64);                  // 512 blocks -> 2 blocks/CU, 8 waves/CU
    seir_euler_kernel<<<grid, block, 0, stream>>>(initial, beta, gamma, sigma, out, B);
}

// Round 4
// 96.497 us; speedup vs baseline: 1.0719x; 1.0719x over previous
//
#include <hip/hip_runtime.h>

#define T_STEPS 1024
#define B_ELEMS 32768
#define STEP 0.5f

typedef float f32x4 __attribute__((ext_vector_type(4)));

__global__ __launch_bounds__(64) void seir_euler_kernel(
    const float* __restrict__ initial,   // (4, B)
    const float* __restrict__ beta,
    const float* __restrict__ gamma,
    const float* __restrict__ sigma,
    f32x4* __restrict__ out)             // (T*B) rows of 4 floats
{
    constexpr int B = B_ELEMS;
    const int b = blockIdx.x * 64 + threadIdx.x;

    const float bb = beta[0];
    const float gg = gamma[0];
    const float ss = sigma[0];

    float S = initial[0 * B + b];
    float E = initial[1 * B + b];
    float I = initial[2 * B + b];
    float R = initial[3 * B + b];

    // Row n = state after n steps; store, then advance. unroll 8 gives the
    // compiler 8 independent store-data register sets -> 8 outstanding
    // nontemporal stores per wave before any vmcnt-forced reuse stall.
    size_t idx = (size_t)b;
#pragma unroll 8
    for (int n = 0; n < T_STEPS; ++n, idx += B) {
        f32x4 v = {S, E, I, R};
        __builtin_nontemporal_store(v, &out[idx]);
        float bSI = bb * S * I;
        float sE  = ss * E;
        float gI  = gg * I;
        float Sn = S - bSI * STEP;
        float En = E + (bSI - sE) * STEP;
        float In = I + (sE - gI) * STEP;
        float Rn = R + gI * STEP;
        S = Sn; E = En; I = In; R = Rn;
    }
}

extern "C" void kernel_launch(void* const* d_in, const int* in_sizes, int n_in,
                              void* d_out, int out_size, void* d_ws, size_t ws_size,
                              hipStream_t stream)
{
    const float* initial = (const float*)d_in[0];
    const float* beta    = (const float*)d_in[1];
    const float* gamma   = (const float*)d_in[2];
    const float* sigma   = (const float*)d_in[3];
    f32x4* out = (f32x4*)d_out;

    const int block = 64;                     // 512 waves -> 2 per CU, all CUs
    const int grid = B_ELEMS / block;         // 512 blocks
    seir_euler_kernel<<<grid, block, 0, stream>>>(initial, beta, gamma, sigma, out);
}